// Round 1
// baseline (111.143 us; speedup 1.0000x reference)
//
#include <hip/hip_runtime.h>
#include <math.h>

#define BB 4
#define NQ 512
#define NK 1024
#define DH 64
#define TQ 8
#define TK 128
#define NCHUNK (NK / TK)   // 8
#define KPAD 65            // +1 pad: bank = (j + d) % 32 -> 2-way only (free)

// ---------------- MLP: k = mlp(x1, Wk*), q = mlp(x2, Wq*) ----------------
// One 64-thread block per output row. relu on layer 1 only.
__global__ __launch_bounds__(64) void mlp_kernel(
    const float* __restrict__ x1, const float* __restrict__ x2,
    const float* __restrict__ Wk1, const float* __restrict__ bk1,
    const float* __restrict__ Wk2, const float* __restrict__ bk2,
    const float* __restrict__ Wq1, const float* __restrict__ bq1,
    const float* __restrict__ Wq2, const float* __restrict__ bq2,
    float* __restrict__ kout, float* __restrict__ qout)
{
    const int row  = blockIdx.x;
    const int lane = threadIdx.x;
    const float *x, *W1, *b1, *W2, *b2;
    float* out;
    if (row < BB * NK) {
        x = x1 + row * DH;
        W1 = Wk1; b1 = bk1; W2 = Wk2; b2 = bk2;
        out = kout + row * DH;
    } else {
        const int rq = row - BB * NK;
        x = x2 + rq * DH;
        W1 = Wq1; b1 = bq1; W2 = Wq2; b2 = bq2;
        out = qout + rq * DH;
    }
    __shared__ float xs[DH];
    __shared__ float hs[DH];
    xs[lane] = x[lane];
    __syncthreads();
    float acc = b1[lane];
    #pragma unroll
    for (int d = 0; d < DH; ++d) acc = fmaf(xs[d], W1[d * DH + lane], acc);
    hs[lane] = fmaxf(acc, 0.0f);     // relu (not on last layer)
    __syncthreads();
    float acc2 = b2[lane];
    #pragma unroll
    for (int d = 0; d < DH; ++d) acc2 = fmaf(hs[d], W2[d * DH + lane], acc2);
    out[lane] = acc2;
}

// ---------------- Laplace attention, flash-style online softmax ----------------
// grid = B * (NQ/TQ) = 256 blocks, 512 threads = 8 waves.
// wave w owns query (i0 + w) for scoring/softmax; for PV wave w owns key range
// [w*16, w*16+16) of the chunk and lane = d.
__global__ __launch_bounds__(512) void attn_kernel(
    const float* __restrict__ kmat, const float* __restrict__ qmat,
    const float* __restrict__ rmat, float* __restrict__ outp)
{
    __shared__ float k_s[TK * KPAD];   // 33.3 KB key chunk; reused for final partials
    __shared__ float p_s[TQ * TK];     // 4 KB current-chunk weights
    __shared__ float alpha_s[TQ];
    __shared__ float linv_s[TQ];

    const int t    = threadIdx.x;
    const int lane = t & 63;
    const int wav  = __builtin_amdgcn_readfirstlane(t >> 6);  // force wave-uniform

    const int b  = blockIdx.x / (NQ / TQ);
    const int qt = blockIdx.x % (NQ / TQ);
    const int i0 = qt * TQ;

    // this wave's q row: wave-uniform address -> scalar loads, stays resident
    const float* qrow = qmat + (b * NQ + i0 + wav) * DH;
    float qreg[DH];
    #pragma unroll
    for (int d = 0; d < DH; ++d) qreg[d] = qrow[d];

    const float* kbase = kmat + (size_t)b * NK * DH;
    const float* rbase = rmat + (size_t)b * NK * DH;

    float M_run = -INFINITY;
    float l_run = 0.0f;
    float O[TQ];
    #pragma unroll
    for (int i = 0; i < TQ; ++i) O[i] = 0.0f;

    for (int c = 0; c < NCHUNK; ++c) {
        // ---- stage k chunk (TK x DH) into padded LDS; float4 global reads ----
        const float4* ksrc = (const float4*)(kbase + c * TK * DH);
        #pragma unroll
        for (int rep = 0; rep < (TK * DH) / (512 * 4); ++rep) {   // 4 reps
            int idx4 = rep * 512 + t;
            float4 v = ksrc[idx4];
            int e  = idx4 * 4;
            int jj = e >> 6;
            int dd = e & 63;
            float* dst = &k_s[jj * KPAD + dd];
            dst[0] = v.x; dst[1] = v.y; dst[2] = v.z; dst[3] = v.w;
        }
        __syncthreads();

        // ---- scores: i = wav, j in {lane, lane+64} ----
        float s0 = 0.0f, s1 = 0.0f;
        #pragma unroll
        for (int d = 0; d < DH; ++d) {
            float q = qreg[d];
            s0 += fabsf(k_s[lane * KPAD + d] - q);          // (lane+d)%32 banks: free
            s1 += fabsf(k_s[(lane + 64) * KPAD + d] - q);
        }
        float sm0 = -s0, sm1 = -s1;

        // ---- online softmax, fully in-wave ----
        float cmax = fmaxf(sm0, sm1);
        #pragma unroll
        for (int off = 32; off > 0; off >>= 1)
            cmax = fmaxf(cmax, __shfl_xor(cmax, off, 64));
        float M_new = fmaxf(M_run, cmax);
        float p0 = __expf(sm0 - M_new);
        float p1 = __expf(sm1 - M_new);
        float csum = p0 + p1;
        #pragma unroll
        for (int off = 32; off > 0; off >>= 1)
            csum += __shfl_xor(csum, off, 64);
        float alpha = __expf(M_run - M_new);   // chunk 0: exp(-inf)=0, O starts at 0
        l_run = l_run * alpha + csum;
        M_run = M_new;
        p_s[wav * TK + lane]      = p0;
        p_s[wav * TK + lane + 64] = p1;
        if (lane == 0) alpha_s[wav] = alpha;
        __syncthreads();

        // ---- PV accumulate: lane = d, wave = key sub-range; r loaded once/block ----
        #pragma unroll
        for (int i = 0; i < TQ; ++i) O[i] *= alpha_s[i];
        const float* rc = rbase + c * TK * DH;
        #pragma unroll
        for (int jj = 0; jj < TK / 8; ++jj) {
            int j = wav * (TK / 8) + jj;
            float rv = rc[j * DH + lane];                   // coalesced 256B
            #pragma unroll
            for (int i = 0; i < TQ; ++i)
                O[i] = fmaf(p_s[i * TK + j], rv, O[i]);     // broadcast LDS read
        }
        __syncthreads();   // protect k_s / p_s before next chunk
    }

    // ---- combine the 8 per-wave PV partials ----
    if (lane == 0) linv_s[wav] = 1.0f / l_run;
    float* part = k_s;   // reuse (needs 8*8*64 = 4096 floats <= TK*KPAD)
    #pragma unroll
    for (int i = 0; i < TQ; ++i)
        part[(wav * TQ + i) * 64 + lane] = O[i];
    __syncthreads();

    float sum = 0.0f;
    #pragma unroll
    for (int g = 0; g < 8; ++g)
        sum += part[(g * TQ + wav) * 64 + lane];
    sum *= linv_s[wav];
    outp[((size_t)b * NQ + i0 + wav) * DH + lane] = sum;
}

extern "C" void kernel_launch(void* const* d_in, const int* in_sizes, int n_in,
                              void* d_out, int out_size, void* d_ws, size_t ws_size,
                              hipStream_t stream) {
    const float* x1  = (const float*)d_in[0];
    const float* x2  = (const float*)d_in[1];
    const float* r   = (const float*)d_in[2];
    const float* Wk1 = (const float*)d_in[3];
    const float* bk1 = (const float*)d_in[4];
    const float* Wk2 = (const float*)d_in[5];
    const float* bk2 = (const float*)d_in[6];
    const float* Wq1 = (const float*)d_in[7];
    const float* bq1 = (const float*)d_in[8];
    const float* Wq2 = (const float*)d_in[9];
    const float* bq2 = (const float*)d_in[10];
    float* out  = (float*)d_out;

    float* kbuf = (float*)d_ws;                  // B*NK*DH floats
    float* qbuf = kbuf + (size_t)BB * NK * DH;   // B*NQ*DH floats

    mlp_kernel<<<BB * (NK + NQ), 64, 0, stream>>>(
        x1, x2, Wk1, bk1, Wk2, bk2, Wq1, bq1, Wq2, bq2, kbuf, qbuf);

    attn_kernel<<<BB * (NQ / TQ), 512, 0, stream>>>(kbuf, qbuf, r, out);
}

// Round 2
// 108.319 us; speedup vs baseline: 1.0261x; 1.0261x over previous
//
#include <hip/hip_runtime.h>
#include <math.h>

#define BB 4
#define NQ 512
#define NK 1024
#define DH 64
#define TQ 8
#define NWAVE 8
#define KPW (NK / NWAVE)   // 128 keys per wave

// ---------------- MLP: writes TRANSPOSED kT[b][d][j], qT[b][d][i] ----------------
// One 64-thread block per output row; lane = output dim e. relu on layer 1 only.
__global__ __launch_bounds__(64) void mlp_kernel(
    const float* __restrict__ x1, const float* __restrict__ x2,
    const float* __restrict__ Wk1, const float* __restrict__ bk1,
    const float* __restrict__ Wk2, const float* __restrict__ bk2,
    const float* __restrict__ Wq1, const float* __restrict__ bq1,
    const float* __restrict__ Wq2, const float* __restrict__ bq2,
    float* __restrict__ kT, float* __restrict__ qT)
{
    const int row  = blockIdx.x;
    const int lane = threadIdx.x;
    const float *x, *W1, *b1, *W2, *b2;
    float* out;   // transposed destination: out[lane * stride]
    if (row < BB * NK) {
        const int b = row / NK, j = row % NK;
        x = x1 + row * DH;
        W1 = Wk1; b1 = bk1; W2 = Wk2; b2 = bk2;
        out = kT + (size_t)b * DH * NK + j;           // + lane*NK below
    } else {
        const int rq = row - BB * NK;
        const int b = rq / NQ, i = rq % NQ;
        x = x2 + rq * DH;
        W1 = Wq1; b1 = bq1; W2 = Wq2; b2 = bq2;
        out = qT + (size_t)b * DH * NQ + i;           // + lane*NQ below
    }
    const int ostride = (row < BB * NK) ? NK : NQ;

    __shared__ float xs[DH];
    __shared__ float hs[DH];
    xs[lane] = x[lane];
    __syncthreads();
    float acc = b1[lane];
    #pragma unroll
    for (int d = 0; d < DH; ++d) acc = fmaf(xs[d], W1[d * DH + lane], acc);
    hs[lane] = fmaxf(acc, 0.0f);     // relu (not on last layer)
    __syncthreads();
    float acc2 = b2[lane];
    #pragma unroll
    for (int d = 0; d < DH; ++d) acc2 = fmaf(hs[d], W2[d * DH + lane], acc2);
    out[lane * ostride] = acc2;      // scattered dword store (transpose)
}

// ---------------- Laplace attention, two-pass softmax, LDS-minimal ----------------
// grid = B * (NQ/TQ) = 256 blocks, 512 threads = 8 waves.
// Score phase: wave w owns keys [w*128, w*128+128), lane holds keys j0=w*128+2*lane, j0+1.
//   kT[d][j] -> coalesced float2 VMEM; qT[d][i0..i0+7] -> wave-uniform (s_load).
// PV phase: lane = d, wave w owns same key range; p broadcast from LDS via b128.
__global__ __launch_bounds__(512) void attn_kernel(
    const float* __restrict__ kT, const float* __restrict__ qT,
    const float* __restrict__ rmat, float* __restrict__ outp)
{
    __shared__ float p_s[TQ * NK];          // 32 KB softmax weights; reused for partials
    __shared__ float wmin_s[NWAVE * TQ];
    __shared__ float wsum_s[NWAVE * TQ];

    const int t    = threadIdx.x;
    const int lane = t & 63;
    const int wav  = __builtin_amdgcn_readfirstlane(t >> 6);

    const int b  = blockIdx.x / (NQ / TQ);
    const int i0 = (blockIdx.x % (NQ / TQ)) * TQ;

    const float* kTb = kT + (size_t)b * DH * NK;
    const float* qTb = qT + (size_t)b * DH * NQ;

    const int j0 = wav * KPW + 2 * lane;    // this lane's two keys

    // ---- score phase: s[i] = sum_d |k[j] - q[i]| , all from registers/VMEM/SMEM ----
    float s0[TQ], s1[TQ];
    #pragma unroll
    for (int i = 0; i < TQ; ++i) { s0[i] = 0.0f; s1[i] = 0.0f; }

    #pragma unroll 8
    for (int d = 0; d < DH; ++d) {
        const float2 kv = *(const float2*)&kTb[d * NK + j0];     // coalesced 512B
        const float* qrow = qTb + d * NQ + i0;                   // uniform -> s_load
        #pragma unroll
        for (int i = 0; i < TQ; ++i) {
            const float q = qrow[i];
            s0[i] += fabsf(kv.x - q);
            s1[i] += fabsf(kv.y - q);
        }
    }

    // ---- softmax pass 1: global min of s per query (max of -s) ----
    #pragma unroll
    for (int i = 0; i < TQ; ++i) {
        float m = fminf(s0[i], s1[i]);
        #pragma unroll
        for (int off = 32; off > 0; off >>= 1)
            m = fminf(m, __shfl_xor(m, off, 64));
        if (lane == 0) wmin_s[wav * TQ + i] = m;
    }
    __syncthreads();

    float M[TQ];
    #pragma unroll
    for (int i = 0; i < TQ; ++i) {
        float m = wmin_s[i];
        #pragma unroll
        for (int g = 1; g < NWAVE; ++g) m = fminf(m, wmin_s[g * TQ + i]);
        M[i] = m;
    }

    // ---- softmax pass 2: p = exp(M - s), per-query sums ----
    #pragma unroll
    for (int i = 0; i < TQ; ++i) {
        const float p0 = __expf(M[i] - s0[i]);
        const float p1 = __expf(M[i] - s1[i]);
        *(float2*)&p_s[i * NK + j0] = make_float2(p0, p1);       // contiguous b64 write
        float cs = p0 + p1;
        #pragma unroll
        for (int off = 32; off > 0; off >>= 1)
            cs += __shfl_xor(cs, off, 64);
        if (lane == 0) wsum_s[wav * TQ + i] = cs;
    }
    __syncthreads();

    // each wave only needs l for its own query (i = wav)
    float myl = 0.0f;
    #pragma unroll
    for (int g = 0; g < NWAVE; ++g) myl += wsum_s[g * TQ + wav];

    // ---- PV: lane = d, wave w covers keys [w*128, w*128+128) ----
    float O[TQ];
    #pragma unroll
    for (int i = 0; i < TQ; ++i) O[i] = 0.0f;

    const float* rb = rmat + ((size_t)b * NK + wav * KPW) * DH;
    for (int jj = 0; jj < KPW; jj += 4) {
        const float rv0 = rb[(jj + 0) * DH + lane];              // coalesced 256B
        const float rv1 = rb[(jj + 1) * DH + lane];
        const float rv2 = rb[(jj + 2) * DH + lane];
        const float rv3 = rb[(jj + 3) * DH + lane];
        #pragma unroll
        for (int i = 0; i < TQ; ++i) {
            const float4 p4 = *(const float4*)&p_s[i * NK + wav * KPW + jj]; // broadcast b128
            O[i] = fmaf(p4.x, rv0, O[i]);
            O[i] = fmaf(p4.y, rv1, O[i]);
            O[i] = fmaf(p4.z, rv2, O[i]);
            O[i] = fmaf(p4.w, rv3, O[i]);
        }
    }
    __syncthreads();    // all waves done reading p_s

    // ---- cross-wave combine (reuse p_s region) ----
    float* part = p_s;  // needs 8*8*64 = 4096 floats <= 8192
    #pragma unroll
    for (int i = 0; i < TQ; ++i)
        part[(wav * TQ + i) * 64 + lane] = O[i];
    __syncthreads();

    float sum = 0.0f;
    #pragma unroll
    for (int g = 0; g < NWAVE; ++g)
        sum += part[(g * TQ + wav) * 64 + lane];
    outp[((size_t)b * NQ + i0 + wav) * DH + lane] = sum / myl;
}

extern "C" void kernel_launch(void* const* d_in, const int* in_sizes, int n_in,
                              void* d_out, int out_size, void* d_ws, size_t ws_size,
                              hipStream_t stream) {
    const float* x1  = (const float*)d_in[0];
    const float* x2  = (const float*)d_in[1];
    const float* r   = (const float*)d_in[2];
    const float* Wk1 = (const float*)d_in[3];
    const float* bk1 = (const float*)d_in[4];
    const float* Wk2 = (const float*)d_in[5];
    const float* bk2 = (const float*)d_in[6];
    const float* Wq1 = (const float*)d_in[7];
    const float* bq1 = (const float*)d_in[8];
    const float* Wq2 = (const float*)d_in[9];
    const float* bq2 = (const float*)d_in[10];
    float* out  = (float*)d_out;

    float* kT = (float*)d_ws;                     // B*DH*NK floats (transposed keys)
    float* qT = kT + (size_t)BB * DH * NK;        // B*DH*NQ floats (transposed queries)

    mlp_kernel<<<BB * (NK + NQ), 64, 0, stream>>>(
        x1, x2, Wk1, bk1, Wk2, bk2, Wq1, bq1, Wq2, bq2, kT, qT);

    attn_kernel<<<BB * (NQ / TQ), 512, 0, stream>>>(kT, qT, r, out);
}